// Round 3
// baseline (357.614 us; speedup 1.0000x reference)
//
#include <hip/hip_runtime.h>

// ---------------------------------------------------------------------------
// ECODQN layer: scatter-mean message passing + 2x (Linear(128->64) + ReLU)
// Inputs (device dtypes per harness contract):
//   0: x         [N,64] f32   1: edge_index [2,E] INT32 (harness converts i64)
//   2: edge_attr [E]    f32   3: x_agg_emb  [N,64] f32
//   4: W_msg [128,64] f32     5: b_msg [64] f32
//   6: W_upd [128,64] f32     7: b_upd [64] f32
// Output: [N,64] fp32
//
// d_ws use kept minimal: counts[N] (~200 KB). d_out doubles as the scatter
// accumulator, then layer1 rewrites it in place with m, then layer2 rewrites
// it in place with the final output. Each layer block stages its 32-node tile
// into LDS before writing that same tile -> in-place is race-free.
// ---------------------------------------------------------------------------

__global__ __launch_bounds__(256) void zero_kernel(float* p, int n) {
    int i = blockIdx.x * 256 + threadIdx.x;
    if (i < n) p[i] = 0.0f;
}

// One wave (64 lanes) per edge; lane d handles feature d.
__global__ __launch_bounds__(256) void scatter_kernel(
    const int* __restrict__ ei, const float* __restrict__ ea,
    const float* __restrict__ x, float* summed,
    float* counts, int E)
{
    int idx = blockIdx.x * 256 + threadIdx.x;
    int e = idx >> 6;
    int d = idx & 63;
    if (e >= E) return;
    int col = ei[e];        // source node (gather)
    int row = ei[E + e];    // destination node (scatter)
    float w = ea[e];
    float v = w * x[(size_t)col * 64 + d];
    atomicAdd(&summed[(size_t)row * 64 + d], v);
    if (d == 0) atomicAdd(&counts[row], 1.0f);
}

// out[n][j] = relu(b[j] + sum_k A1[n][k]*W[k][j] + sum_k A2[n][k]*W[64+k][j])
// If counts != nullptr, A1 rows are divided by max(counts[n],1) (scatter-mean).
// A1/A2/out MAY alias (in-place per-tile rewrite) -- no __restrict__ here.
// Tile: 32 nodes/block; thread = (jg in [0,16): 4 cols, ng in [0,16): 2 nodes).
__global__ __launch_bounds__(256) void layer_kernel(
    const float* A1, const float* A2,
    const float* __restrict__ counts,
    const float* __restrict__ W, const float* __restrict__ b,
    float* out, int N)
{
    // stride 69: lanes read a1s[2*ng*69 + k]; 138 % 32 = 10 spreads the 16
    // ng-values over 16 distinct banks (stride 68 gave a 4-way conflict).
    __shared__ __align__(16) float Ws[128 * 64];   // 32 KB
    __shared__ __align__(16) float a1s[32 * 69];
    __shared__ __align__(16) float a2s[32 * 69];
    __shared__ __align__(16) float bs[64];

    const int t = threadIdx.x;

    // Stage W: 8192 floats = 2048 float4, 8 per thread.
    const float4* Wg = (const float4*)W;
    float4* Wsv = (float4*)Ws;
    #pragma unroll
    for (int i = 0; i < 8; i++)
        Wsv[t + i * 256] = Wg[t + i * 256];
    if (t < 64) bs[t] = b[t];

    // Stage activations for this 32-node tile.
    const int tile0 = blockIdx.x * 32;
    for (int i = t; i < 2048; i += 256) {
        int nn = i >> 6, d = i & 63;
        int n = tile0 + nn;
        float v1 = 0.f, v2 = 0.f;
        if (n < N) {
            v1 = A1[(size_t)n * 64 + d];
            if (counts) v1 /= fmaxf(counts[n], 1.0f);
            v2 = A2[(size_t)n * 64 + d];
        }
        a1s[nn * 69 + d] = v1;
        a2s[nn * 69 + d] = v2;
    }
    __syncthreads();   // all tile reads complete before any in-place writes

    const int jg = t & 15;        // cols 4*jg .. 4*jg+3
    const int ng = t >> 4;        // nodes 2*ng, 2*ng+1 (in-tile)
    const int n0 = ng * 2, n1 = n0 + 1;

    float4 bb = ((const float4*)bs)[jg];
    float4 acc0 = bb, acc1 = bb;
    const float4* Wv = (const float4*)Ws;   // Wv[k*16 + jg] = W[k][4jg..4jg+3]

    #pragma unroll 8
    for (int k = 0; k < 64; k++) {
        float4 w = Wv[k * 16 + jg];
        float a = a1s[n0 * 69 + k];
        float c = a1s[n1 * 69 + k];
        acc0.x += a * w.x; acc0.y += a * w.y; acc0.z += a * w.z; acc0.w += a * w.w;
        acc1.x += c * w.x; acc1.y += c * w.y; acc1.z += c * w.z; acc1.w += c * w.w;
    }
    #pragma unroll 8
    for (int k = 0; k < 64; k++) {
        float4 w = Wv[(64 + k) * 16 + jg];
        float a = a2s[n0 * 69 + k];
        float c = a2s[n1 * 69 + k];
        acc0.x += a * w.x; acc0.y += a * w.y; acc0.z += a * w.z; acc0.w += a * w.w;
        acc1.x += c * w.x; acc1.y += c * w.y; acc1.z += c * w.z; acc1.w += c * w.w;
    }

    float4 r0 = make_float4(fmaxf(acc0.x, 0.f), fmaxf(acc0.y, 0.f),
                            fmaxf(acc0.z, 0.f), fmaxf(acc0.w, 0.f));
    float4 r1 = make_float4(fmaxf(acc1.x, 0.f), fmaxf(acc1.y, 0.f),
                            fmaxf(acc1.z, 0.f), fmaxf(acc1.w, 0.f));
    int gn0 = tile0 + n0, gn1 = tile0 + n1;
    if (gn0 < N) ((float4*)out)[(size_t)gn0 * 16 + jg] = r0;
    if (gn1 < N) ((float4*)out)[(size_t)gn1 * 16 + jg] = r1;
}

extern "C" void kernel_launch(void* const* d_in, const int* in_sizes, int n_in,
                              void* d_out, int out_size, void* d_ws, size_t ws_size,
                              hipStream_t stream) {
    const float* x   = (const float*)d_in[0];
    const int*   ei  = (const int*)d_in[1];     // int32 on device (harness)
    const float* ea  = (const float*)d_in[2];
    const float* emb = (const float*)d_in[3];
    const float* Wm  = (const float*)d_in[4];
    const float* bm  = (const float*)d_in[5];
    const float* Wu  = (const float*)d_in[6];
    const float* bu  = (const float*)d_in[7];
    float*       out = (float*)d_out;

    const int N = in_sizes[0] / 64;
    const int E = in_sizes[2];

    float* counts = (float*)d_ws;   // N floats (~200 KB) -- only ws use
    float* summed = out;            // accumulate scatter directly in d_out
    float* m      = out;            // layer1 rewrites d_out in place

    // 1) zero accumulators (both are poisoned 0xAA before every launch)
    zero_kernel<<<(N * 64 + 255) / 256, 256, 0, stream>>>(summed, N * 64);
    zero_kernel<<<(N + 255) / 256, 256, 0, stream>>>(counts, N);

    // 2) edge scatter (weighted gather + atomic scatter-add + counts)
    long long total = (long long)E * 64;
    scatter_kernel<<<(int)((total + 255) / 256), 256, 0, stream>>>(
        ei, ea, x, summed, counts, E);

    // 3) layer 1 (in place): m = relu([x_agg, x_agg_emb] @ W_msg + b_msg)
    int blocks = (N + 31) / 32;
    layer_kernel<<<blocks, 256, 0, stream>>>(summed, emb, counts, Wm, bm, m, N);

    // 4) layer 2 (in place): out = relu([x, m] @ W_upd + b_upd)
    layer_kernel<<<blocks, 256, 0, stream>>>(x, m, nullptr, Wu, bu, out, N);
}